// Round 1
// 418.776 us; speedup vs baseline: 1.0869x; 1.0869x over previous
//
#include <hip/hip_runtime.h>

// LGA (GANet Local Guided Aggregation), radius=2, K=5.
// in1: [N=4, C=32, H=384, W=768] f32
// in2: [N=4, 25,   H=384, W=768] f32 (per-pixel 5x5 taps, shared across C)
// out: [N, C, H, W] f32
//
// v2 strategy: previous version's wt[25] (100 VGPRs) was sunk back into the
// channel loop by the compiler (VGPR_Count=64 observed) -> 3.8 GB of L2
// weight re-reads + latency-bound inner loop. Fixes:
//  1. asm-pin the 25 float4 taps so they stay resident in VGPRs.
//  2. LDS double-buffer + async-split staging (issue global loads early,
//     ds_write after compute) -> one barrier per channel, HBM latency
//     hidden under the 100-FMA compute phase.

#define N_DIM 4
#define C_DIM 32
#define H_DIM 384
#define W_DIM 768
#define HW (H_DIM * W_DIM)
#define TH 4          // output rows per block
#define TW 256        // output cols per block (64 lanes x 4 pixels)
#define LROWS (TH + 4)
#define LW 260        // LDS row stride in floats: cols [w0-2, w0+258)
#define CHUNKS (LROWS * 65)   // 520 float4 chunks per buffer

__global__ __launch_bounds__(256, 3)
void lga_kernel(const float* __restrict__ in1,
                const float* __restrict__ in2,
                float* __restrict__ out) {
    __shared__ float lds[2][LROWS * LW];   // 2 x 8.32 KB

    const int tid = threadIdx.x;
    const int tx  = tid & 63;   // lane within wave
    const int ty  = tid >> 6;   // wave index = output row within tile
    const int w0  = blockIdx.x * TW;
    const int h0  = blockIdx.y * TH;
    const int n   = blockIdx.z;

    const int h  = h0 + ty;          // this thread's output row
    const int wb = w0 + 4 * tx;      // first of 4 output cols

    // ---- 25 per-pixel tap weights, FORCED resident in VGPRs ----
    // The empty asm with "+v" makes each value an asm-def: the compiler can
    // no longer rematerialize the load inside the channel loop (v1 did
    // exactly that at VGPR_Count=64, costing ~3.8 GB of L2 re-reads).
    float4 wt[25];
    {
        const float* w_src = in2 + ((size_t)n * 25) * HW + (size_t)h * W_DIM + wb;
#pragma unroll
        for (int t = 0; t < 25; ++t) {
            float4 v = *(const float4*)(w_src + (size_t)t * HW);
            asm volatile("" : "+v"(v.x), "+v"(v.y), "+v"(v.z), "+v"(v.w));
            wt[t] = v;
        }
    }

    const float* in1_n = in1 + (size_t)n * C_DIM * HW;
    float*       out_n = out + (size_t)n * C_DIM * HW;

    // ---- precomputed staging descriptors: chunks tid, tid+256, tid+512 ----
    // chunk idx -> row = idx/65, c4 = idx%65; LDS col L maps to global col
    // (w0 - 2 + L); each chunk is 4 floats, 16B-aligned in LDS.
    int  soff[3];   // gh*W + g  (row base + col; valid when rok)
    int  ldst[3];   // LDS float offset
    int  gcol[3];   // global col of chunk start (== 2 mod 4)
    bool fast[3];   // fully interior chunk
    bool rok[3];    // row in range
    bool act[3];    // chunk exists (3rd chunk: tid < 8)
#pragma unroll
    for (int k = 0; k < 3; ++k) {
        const int idx = tid + 256 * k;
        act[k] = (k < 2) || (tid < CHUNKS - 512);
        const int row = idx / 65;
        const int c4  = idx - row * 65;
        const int gh  = h0 - 2 + row;
        const int g   = w0 - 2 + 4 * c4;
        rok[k]  = (unsigned)gh < H_DIM;
        gcol[k] = g;
        fast[k] = rok[k] && (g >= 0) && (g + 3 < W_DIM);
        soff[k] = (rok[k] ? gh : 0) * W_DIM + g;
        ldst[k] = row * LW + 4 * c4;
    }

    auto load_chunk = [&](const float* src, int k) -> float4 {
        float4 v;
        if (fast[k]) {
            const float* p = src + soff[k];          // 8B aligned (g == 2 mod 4)
            const float2 a = *(const float2*)p;
            const float2 b = *(const float2*)(p + 2);
            v = make_float4(a.x, a.y, b.x, b.y);
        } else {
            const int g = gcol[k];
            const float* prow = src + (soff[k] - g); // row base (valid iff rok)
            v.x = (rok[k] && (unsigned)(g + 0) < W_DIM) ? prow[g + 0] : 0.f;
            v.y = (rok[k] && (unsigned)(g + 1) < W_DIM) ? prow[g + 1] : 0.f;
            v.z = (rok[k] && (unsigned)(g + 2) < W_DIM) ? prow[g + 2] : 0.f;
            v.w = (rok[k] && (unsigned)(g + 3) < W_DIM) ? prow[g + 3] : 0.f;
        }
        return v;
    };

    // ---- prologue: stage channel 0 into lds[0] ----
    {
        float4 v0 = load_chunk(in1_n, 0);
        float4 v1 = load_chunk(in1_n, 1);
        float4 v2 = make_float4(0.f, 0.f, 0.f, 0.f);
        if (act[2]) v2 = load_chunk(in1_n, 2);
        *(float4*)&lds[0][ldst[0]] = v0;
        *(float4*)&lds[0][ldst[1]] = v1;
        if (act[2]) *(float4*)&lds[0][ldst[2]] = v2;
    }
    __syncthreads();

    for (int c = 0; c < C_DIM; ++c) {
        const int  cur  = c & 1;
        const bool more = (c + 1 < C_DIM);      // uniform across block

        // (1) issue next channel's global loads (latency hides under compute)
        float4 n0, n1, n2 = make_float4(0.f, 0.f, 0.f, 0.f);
        if (more) {
            const float* src = in1_n + (size_t)(c + 1) * HW;
            n0 = load_chunk(src, 0);
            n1 = load_chunk(src, 1);
            if (act[2]) n2 = load_chunk(src, 2);
        }

        // (2) compute 4 pixels from lds[cur]
        float acc0 = 0.f, acc1 = 0.f, acc2 = 0.f, acc3 = 0.f;
        const float* lbase = &lds[cur][0];
#pragma unroll
        for (int i = 0; i < 5; ++i) {
            const float* lrow = lbase + (ty + i) * LW + 4 * tx;  // global col wb-2
            const float4 A = *(const float4*)lrow;               // win[0..3]
            const float4 B = *(const float4*)(lrow + 4);         // win[4..7]
            const float win[8] = {A.x, A.y, A.z, A.w, B.x, B.y, B.z, B.w};
#pragma unroll
            for (int j = 0; j < 5; ++j) {
                const float4 wv = wt[5 * i + j];
                acc0 += wv.x * win[j + 0];
                acc1 += wv.y * win[j + 1];
                acc2 += wv.z * win[j + 2];
                acc3 += wv.w * win[j + 3];
            }
        }

        *(float4*)(out_n + (size_t)c * HW + (size_t)h * W_DIM + wb)
            = make_float4(acc0, acc1, acc2, acc3);

        // (3) write next tile into the other buffer, one barrier per channel
        if (more) {
            float* dst = &lds[cur ^ 1][0];
            *(float4*)&dst[ldst[0]] = n0;
            *(float4*)&dst[ldst[1]] = n1;
            if (act[2]) *(float4*)&dst[ldst[2]] = n2;
            __syncthreads();
        }
    }
}

extern "C" void kernel_launch(void* const* d_in, const int* in_sizes, int n_in,
                              void* d_out, int out_size, void* d_ws, size_t ws_size,
                              hipStream_t stream) {
    const float* in1 = (const float*)d_in[0];
    const float* in2 = (const float*)d_in[1];
    float* out = (float*)d_out;
    dim3 grid(W_DIM / TW, H_DIM / TH, N_DIM);   // (3, 96, 4)
    lga_kernel<<<grid, 256, 0, stream>>>(in1, in2, out);
}